// Round 10
// baseline (156.985 us; speedup 1.0000x reference)
//
#include <hip/hip_runtime.h>
#include <stdint.h>

#define P_TOT 2304
#define C_IN  256
#define INTER 128
#define NH    8
#define HD    16
#define NKB   144   // P_TOT/16 key/query tiles
// fold 1/sqrt(16) * log2(e) into Q so attention does exp2(S) directly
#define QSCALE 0.36067376022224087f

typedef short sh4 __attribute__((ext_vector_type(4)));
typedef short sh8 __attribute__((ext_vector_type(8)));
typedef float fl4 __attribute__((ext_vector_type(4)));

static __device__ __forceinline__ unsigned short f2bf(float f) {
    union { float f; unsigned u; } v; v.f = f;
    return (unsigned short)((v.u + 0x7fffu + ((v.u >> 16) & 1u)) >> 16);
}
// pack two floats as bf16 pair, round-half-up (1 perm + 2 adds)
static __device__ __forceinline__ unsigned pack_bf2(float a, float b) {
    union { float f; unsigned u; } x, y; x.f = a; y.f = b;
    return __builtin_amdgcn_perm(y.u + 0x8000u, x.u + 0x8000u, 0x07060302u);
}
// truncating pack (1 perm). Downward bias cancels in softmax normalization.
static __device__ __forceinline__ unsigned pack_bf2_trunc(float a, float b) {
    union { float f; unsigned u; } x, y; x.f = a; y.f = b;
    return __builtin_amdgcn_perm(y.u, x.u, 0x07060302u);
}

// ---------------- Kernel 0: weights f32 -> bf16. Wb: [Wq][Wk][Wv][Wo] 32768 each.
__global__ __launch_bounds__(256) void k_prep(
    const float* __restrict__ Wq, const float* __restrict__ Wk,
    const float* __restrict__ Wv, const float* __restrict__ Wo,
    unsigned short* __restrict__ Wb) {
    int i = blockIdx.x * 256 + threadIdx.x;
    int seg = i >> 15, off = i & 32767;
    const float* s = (seg == 0 ? Wq : (seg == 1 ? Wk : (seg == 2 ? Wv : Wo)));
    Wb[i] = f2bf(s[off]);
}

// ---------------- Kernel 1: QKV projection, LDS-free loads, 2-way C-split.
// grid (72 p-tiles of 32, 12 = pr*4+b), 256 thr = 4 waves.
// Q/K/V written in MFMA-FRAGMENT-TILED layout: tensor[bh][tile(144)][256 halfs],
// lane (l15,quad) offset (quad*16+l15)*4 -> wave-contiguous 512B loads AND stores.
//   Q/K tile element (quad,l15,j) = X[p=tile*16+l15][d=quad*4+j]   (B/A frag of QK)
//   V   tile element (quad,l15,j) = V[d=l15][kpos=quad*4+j]        (A frag of PV)
__global__ __launch_bounds__(256) void k_qkv(
    const float* __restrict__ rgb, const float* __restrict__ depth,
    const float* __restrict__ rgbd, const unsigned short* __restrict__ Wb,
    const float* __restrict__ bq, const float* __restrict__ bk,
    const float* __restrict__ bv,
    unsigned short* __restrict__ Qt, unsigned short* __restrict__ Kt,
    unsigned short* __restrict__ Vn) {
    __shared__ fl4 ldsA[2][8][64]; // [p-sub][mf][lane] partials from c-half 1
    int nt = blockIdx.x, pb = blockIdx.y;
    int pr = pb >> 2, b = pb & 3;
    const unsigned short* W = Wb + pr * (INTER * C_IN);
    const float* bias = (pr == 0 ? bq : (pr == 1 ? bk : bv));
    const float* X = (pr == 0 ? rgb : (pr == 1 ? depth : rgbd)) + (size_t)b * C_IN * P_TOT;
    int tid = threadIdx.x, w = tid >> 6, lane = tid & 63;
    int wp = w & 1, chalf = w >> 1;
    int l15 = lane & 15, quad = lane >> 4;
    int p = nt * 32 + wp * 16 + l15;
    fl4 zero = {0.f, 0.f, 0.f, 0.f};
    fl4 acc[8];
#pragma unroll
    for (int i = 0; i < 8; ++i) acc[i] = zero;
    const float* xcol = X + p;
    int kbeg = chalf * 128;
#pragma unroll
    for (int kk = 0; kk < 128; kk += 32) {
        int k0 = kbeg + kk;
        int cb = k0 + quad * 8;
        unsigned u[8];
#pragma unroll
        for (int j = 0; j < 8; ++j) {
            union { float f; unsigned uu; } t;
            t.f = xcol[(size_t)(cb + j) * P_TOT];
            u[j] = t.uu;
        }
        sh8 bfr;
        unsigned* bu = (unsigned*)&bfr;
        bu[0] = __builtin_amdgcn_perm(u[1] + 0x8000u, u[0] + 0x8000u, 0x07060302u);
        bu[1] = __builtin_amdgcn_perm(u[3] + 0x8000u, u[2] + 0x8000u, 0x07060302u);
        bu[2] = __builtin_amdgcn_perm(u[5] + 0x8000u, u[4] + 0x8000u, 0x07060302u);
        bu[3] = __builtin_amdgcn_perm(u[7] + 0x8000u, u[6] + 0x8000u, 0x07060302u);
        if (pr < 2) {
#pragma unroll
            for (int mf = 0; mf < 8; ++mf) {
                sh8 af = *(const sh8*)(W + (size_t)(mf * 16 + l15) * C_IN + k0 + quad * 8);
                acc[mf] = __builtin_amdgcn_mfma_f32_16x16x32_bf16(af, bfr, acc[mf], 0, 0, 0);
            }
        } else {
#pragma unroll
            for (int mf = 0; mf < 8; ++mf) {
                sh8 af = *(const sh8*)(W + (size_t)(mf * 16 + l15) * C_IN + k0 + quad * 8);
                // swapped: C col = W-row (channel), C row = p offset
                acc[mf] = __builtin_amdgcn_mfma_f32_16x16x32_bf16(bfr, af, acc[mf], 0, 0, 0);
            }
        }
    }
    if (chalf == 1) {
#pragma unroll
        for (int mf = 0; mf < 8; ++mf) ldsA[wp][mf][lane] = acc[mf];
    }
    __syncthreads();
    if (chalf == 1) return;
#pragma unroll
    for (int mf = 0; mf < 8; ++mf) acc[mf] += ldsA[wp][mf][lane];
    int tile = nt * 2 + wp;          // p >> 4
    int loff = (quad * 16 + l15) * 4;
    if (pr < 2) {
        unsigned short* dst0 = (pr == 0 ? Qt : Kt);
        float sc = (pr == 0 ? QSCALE : 1.0f);
#pragma unroll
        for (int mf = 0; mf < 8; ++mf) {
            float4 bb = *(const float4*)(bias + mf * 16 + quad * 4);
            uint2 v;
            v.x = pack_bf2((acc[mf][0] + bb.x) * sc, (acc[mf][1] + bb.y) * sc);
            v.y = pack_bf2((acc[mf][2] + bb.z) * sc, (acc[mf][3] + bb.w) * sc);
            *(uint2*)(dst0 + (size_t)((b * NH + mf) * NKB + tile) * 256 + loff) = v;
        }
    } else {
#pragma unroll
        for (int mf = 0; mf < 8; ++mf) {
            float bb = bias[mf * 16 + l15];
            uint2 v;
            v.x = pack_bf2(acc[mf][0] + bb, acc[mf][1] + bb);
            v.y = pack_bf2(acc[mf][2] + bb, acc[mf][3] + bb);
            *(uint2*)(Vn + (size_t)((b * NH + mf) * NKB + tile) * 256 + loff) = v;
        }
    }
}

// ---------------- Kernel 2: attention, no-max softmax (scores bounded ~|3|),
// raw v_exp_f32, fragment-tiled coalesced loads (512B/wave per dwordx2).
// grid (36 q-tiles of 64, 8 h, 4 b), 512 thr = 8 waves; each wave: same 64 q
// (4 streams), its own 1/8 of the 2304 keys (18 tiles); partials tree-combined
// via LDS (exact: fixed shift 0 => plain sums).
__global__ __launch_bounds__(512) void k_attn(
    const unsigned short* __restrict__ Qt, const unsigned short* __restrict__ Kt,
    const unsigned short* __restrict__ Vn, unsigned short* __restrict__ Ot) {
    __shared__ fl4 red[4][5][64];
    int qt = blockIdx.x, h = blockIdx.y, b = blockIdx.z;
    int tid = threadIdx.x, w = tid >> 6, lane = tid & 63;
    int l15 = lane & 15, quad = lane >> 4;
    int bh = b * NH + h;
    int loff = (quad * 16 + l15) * 4;
    const unsigned short* qb = Qt + (size_t)(bh * NKB + qt * 4) * 256 + loff;
    sh4 qf0 = *(const sh4*)(qb);
    sh4 qf1 = *(const sh4*)(qb + 256);
    sh4 qf2 = *(const sh4*)(qb + 512);
    sh4 qf3 = *(const sh4*)(qb + 768);
    const int NIT = NKB / 8; // 18 tiles per wave
    const unsigned short* kb = Kt + (size_t)(bh * NKB + w * NIT) * 256 + loff;
    const unsigned short* vb = Vn + (size_t)(bh * NKB + w * NIT) * 256 + loff;
    fl4 zero = {0.f, 0.f, 0.f, 0.f};
    fl4 o0 = zero, o1 = zero, o2 = zero, o3 = zero;
    fl4 ls = zero;
    sh4 kf = *(const sh4*)kb;
    sh4 vf = *(const sh4*)vb;
    for (int it = 0; it < NIT; ++it) {
        int nx = (it + 1 < NIT) ? it + 1 : it;
        sh4 kf_n = *(const sh4*)(kb + (size_t)nx * 256);
        sh4 vf_n = *(const sh4*)(vb + (size_t)nx * 256);
        fl4 s0 = __builtin_amdgcn_mfma_f32_16x16x16bf16_1k(kf, qf0, zero, 0, 0, 0);
        fl4 s1 = __builtin_amdgcn_mfma_f32_16x16x16bf16_1k(kf, qf1, zero, 0, 0, 0);
        fl4 s2 = __builtin_amdgcn_mfma_f32_16x16x16bf16_1k(kf, qf2, zero, 0, 0, 0);
        fl4 s3 = __builtin_amdgcn_mfma_f32_16x16x16bf16_1k(kf, qf3, zero, 0, 0, 0);
        float e00 = __builtin_amdgcn_exp2f(s0[0]), e01 = __builtin_amdgcn_exp2f(s0[1]);
        float e02 = __builtin_amdgcn_exp2f(s0[2]), e03 = __builtin_amdgcn_exp2f(s0[3]);
        float e10 = __builtin_amdgcn_exp2f(s1[0]), e11 = __builtin_amdgcn_exp2f(s1[1]);
        float e12 = __builtin_amdgcn_exp2f(s1[2]), e13 = __builtin_amdgcn_exp2f(s1[3]);
        float e20 = __builtin_amdgcn_exp2f(s2[0]), e21 = __builtin_amdgcn_exp2f(s2[1]);
        float e22 = __builtin_amdgcn_exp2f(s2[2]), e23 = __builtin_amdgcn_exp2f(s2[3]);
        float e30 = __builtin_amdgcn_exp2f(s3[0]), e31 = __builtin_amdgcn_exp2f(s3[1]);
        float e32 = __builtin_amdgcn_exp2f(s3[2]), e33 = __builtin_amdgcn_exp2f(s3[3]);
        ls[0] += (e00 + e01) + (e02 + e03);
        ls[1] += (e10 + e11) + (e12 + e13);
        ls[2] += (e20 + e21) + (e22 + e23);
        ls[3] += (e30 + e31) + (e32 + e33);
        sh4 pf0, pf1, pf2, pf3;
        ((unsigned*)&pf0)[0] = pack_bf2_trunc(e00, e01);
        ((unsigned*)&pf0)[1] = pack_bf2_trunc(e02, e03);
        ((unsigned*)&pf1)[0] = pack_bf2_trunc(e10, e11);
        ((unsigned*)&pf1)[1] = pack_bf2_trunc(e12, e13);
        ((unsigned*)&pf2)[0] = pack_bf2_trunc(e20, e21);
        ((unsigned*)&pf2)[1] = pack_bf2_trunc(e22, e23);
        ((unsigned*)&pf3)[0] = pack_bf2_trunc(e30, e31);
        ((unsigned*)&pf3)[1] = pack_bf2_trunc(e32, e33);
        o0 = __builtin_amdgcn_mfma_f32_16x16x16bf16_1k(vf, pf0, o0, 0, 0, 0);
        o1 = __builtin_amdgcn_mfma_f32_16x16x16bf16_1k(vf, pf1, o1, 0, 0, 0);
        o2 = __builtin_amdgcn_mfma_f32_16x16x16bf16_1k(vf, pf2, o2, 0, 0, 0);
        o3 = __builtin_amdgcn_mfma_f32_16x16x16bf16_1k(vf, pf3, o3, 0, 0, 0);
        kf = kf_n;
        vf = vf_n;
    }
    // tree combine across 8 waves (3 rounds)
#pragma unroll
    for (int step = 4; step >= 1; step >>= 1) {
        if (w >= step && w < 2 * step) {
            red[w - step][0][lane] = o0;
            red[w - step][1][lane] = o1;
            red[w - step][2][lane] = o2;
            red[w - step][3][lane] = o3;
            red[w - step][4][lane] = ls;
        }
        __syncthreads();
        if (w < step) {
            o0 += red[w][0][lane];
            o1 += red[w][1][lane];
            o2 += red[w][2][lane];
            o3 += red[w][3][lane];
            ls += red[w][4][lane];
        }
        __syncthreads();
    }
    if (w != 0) return;
#pragma unroll
    for (int i = 0; i < 4; ++i) {
        ls[i] += __shfl_xor(ls[i], 16);
        ls[i] += __shfl_xor(ls[i], 32);
    }
    float i0 = 1.f / ls[0], i1 = 1.f / ls[1], i2 = 1.f / ls[2], i3 = 1.f / ls[3];
    int q0 = qt * 64 + l15;
    unsigned short* ob = Ot + (size_t)bh * P_TOT * HD + quad * 4;
    uint2 v;
    v.x = pack_bf2(o0[0] * i0, o0[1] * i0); v.y = pack_bf2(o0[2] * i0, o0[3] * i0);
    *(uint2*)(ob + (size_t)q0 * HD) = v;
    v.x = pack_bf2(o1[0] * i1, o1[1] * i1); v.y = pack_bf2(o1[2] * i1, o1[3] * i1);
    *(uint2*)(ob + (size_t)(q0 + 16) * HD) = v;
    v.x = pack_bf2(o2[0] * i2, o2[1] * i2); v.y = pack_bf2(o2[2] * i2, o2[3] * i2);
    *(uint2*)(ob + (size_t)(q0 + 32) * HD) = v;
    v.x = pack_bf2(o3[0] * i3, o3[1] * i3); v.y = pack_bf2(o3[2] * i3, o3[3] * i3);
    *(uint2*)(ob + (size_t)(q0 + 48) * HD) = v;
}

// ---------------- Kernel 3: output projection + bias + 3 residuals, f32,
// swapped MFMA (lane holds 4 consecutive p). One mf (16 ch) per wave ->
// grid (144 p-tiles of 16, 4 mf-groups, 4 b) x 4 waves = 9216 waves (9/SIMD).
__global__ __launch_bounds__(256) void k_out(
    const unsigned short* __restrict__ Ot, const unsigned short* __restrict__ Wob,
    const float* __restrict__ bo, const float* __restrict__ rgb,
    const float* __restrict__ depth, const float* __restrict__ rgbd,
    float* __restrict__ out) {
    int nt = blockIdx.x, mg = blockIdx.y, b = blockIdx.z;
    int tid = threadIdx.x, w = tid >> 6, lane = tid & 63;
    int l15 = lane & 15, quad = lane >> 4;
    int mf = mg * 4 + w;
    int p0 = nt * 16;
    fl4 zero = {0.f, 0.f, 0.f, 0.f};
    fl4 acc = zero;
#pragma unroll
    for (int k0 = 0; k0 < INTER; k0 += 32) {
        int h = (k0 >> 4) + (quad >> 1);
        int doff = 8 * (quad & 1);
        sh8 bfr = *(const sh8*)(Ot + ((size_t)(b * NH + h) * P_TOT + p0 + l15) * HD + doff);
        sh8 af = *(const sh8*)(Wob + (size_t)(mf * 16 + l15) * INTER + k0 + quad * 8);
        // swapped: C col = Wo-row (channel), C row = p offset
        acc = __builtin_amdgcn_mfma_f32_16x16x32_bf16(bfr, af, acc, 0, 0, 0);
    }
    const size_t outsz = (size_t)4 * C_IN * P_TOT;
    int ch = mf * 16 + l15;
    float bb = bo[ch];
    size_t idx = ((size_t)b * C_IN + ch) * P_TOT + p0 + quad * 4;
    float r0 = acc[0] + bb, r1 = acc[1] + bb, r2 = acc[2] + bb, r3 = acc[3] + bb;
    float4 a = *(const float4*)(rgb + idx);
    float4 d = *(const float4*)(depth + idx);
    float4 g = *(const float4*)(rgbd + idx);
    float4 o;
    o.x = a.x + r0; o.y = a.y + r1; o.z = a.z + r2; o.w = a.w + r3;
    *(float4*)(out + idx) = o;
    o.x = d.x + r0; o.y = d.y + r1; o.z = d.z + r2; o.w = d.w + r3;
    *(float4*)(out + outsz + idx) = o;
    o.x = g.x + r0; o.y = g.y + r1; o.z = g.z + r2; o.w = g.w + r3;
    *(float4*)(out + 2 * outsz + idx) = o;
}

extern "C" void kernel_launch(void* const* d_in, const int* in_sizes, int n_in,
                              void* d_out, int out_size, void* d_ws, size_t ws_size,
                              hipStream_t stream) {
    (void)in_sizes; (void)n_in; (void)out_size; (void)ws_size;
    const float* rgb   = (const float*)d_in[0];
    const float* depth = (const float*)d_in[1];
    const float* rgbd  = (const float*)d_in[2];
    const float* Wq = (const float*)d_in[3];
    const float* bq = (const float*)d_in[4];
    const float* Wk = (const float*)d_in[5];
    const float* bk = (const float*)d_in[6];
    const float* Wv = (const float*)d_in[7];
    const float* bv = (const float*)d_in[8];
    const float* Wo = (const float*)d_in[9];
    const float* bo = (const float*)d_in[10];

    // ALL scratch now in d_ws (~9.7 MB of ~256 MB): d_out is write-only
    // (only k_out touches it) -> no read-after-write aliasing with any
    // harness-poisoned buffer; output is a pure function of d_in each launch.
    float* outp = (float*)d_out;
    unsigned short* Ot = (unsigned short*)d_ws;                 // 1,179,648 halfs
    unsigned short* Wb = Ot + (size_t)4 * P_TOT * INTER;        //   131,072 halfs
    unsigned short* Qt = Wb + (size_t)4 * 32768;                // 1,179,648 halfs
    unsigned short* Kt = Qt + (size_t)4 * P_TOT * INTER;
    unsigned short* Vn = Kt + (size_t)4 * P_TOT * INTER;

    k_prep<<<512, 256, 0, stream>>>(Wq, Wk, Wv, Wo, Wb);
    k_qkv<<<dim3(72, 12), 256, 0, stream>>>(rgb, depth, rgbd, Wb, bq, bk, bv, Qt, Kt, Vn);
    k_attn<<<dim3(36, NH, 4), 512, 0, stream>>>(Qt, Kt, Vn, Ot);
    k_out<<<dim3(144, 4, 4), 256, 0, stream>>>(Ot, Wb + 3 * 32768, bo, rgb, depth, rgbd, outp);
}